// Round 1
// 222.473 us; speedup vs baseline: 1.0037x; 1.0037x over previous
//
#include <hip/hip_runtime.h>

// B=2, T=2048, C=1024, H=16, D=64. Inputs fp32, OUTPUT fp32.
// Round 13: flash_k restructured — double-buffered K/V LDS with async-STAGE
// split (issue global loads at top of iter, ds_write after compute, ONE
// barrier per k-tile), base-2 softmax (log2e folded into q scale in qkv),
// defer-max rescale (THR=8), strip-invariant V fragments hoisted,
// complementary strip assignment (rows w*16 and 112-w*16 per wave) for exact
// per-wave causal balance. Rest = round 12.
// MFMA 16x16x32_bf16 layouts (HW-verified): A: m=lane&15,k=quad*8+j;
// B: k=quad*8+j,n=lane&15; C/D: col=lane&15,row=quad*4+reg.

typedef unsigned short u16;
typedef u16 u16x4 __attribute__((ext_vector_type(4)));
typedef u16 u16x8 __attribute__((ext_vector_type(8)));
typedef short s16x8 __attribute__((ext_vector_type(8)));
typedef float f32x4 __attribute__((ext_vector_type(4)));

#define T_SEQ 2048
#define C_EMB 1024
#define NH 16
#define HD 64

#define MFMA16(a, b, c) __builtin_amdgcn_mfma_f32_16x16x32_bf16(a, b, c, 0, 0, 0)

__device__ __forceinline__ u16 f2bf(float f) {
    union { float f; unsigned int i; } x; x.f = f;
    unsigned int r = x.i + 0x7fffu + ((x.i >> 16) & 1u);
    return (u16)(r >> 16);
}
__device__ __forceinline__ u16x4 pack4(f32x4 v) {
    u16x4 o;
#pragma unroll
    for (int j = 0; j < 4; ++j) o[j] = f2bf(v[j]);
    return o;
}

// ---------------- k0a: fp32 -> bf16 convert ----------------
__global__ __launch_bounds__(256) void conv_k(const float* __restrict__ src, u16* __restrict__ dst, int n8) {
    int i = blockIdx.x * 256 + threadIdx.x;
    if (i >= n8) return;
    f32x4 a = ((const f32x4*)src)[i * 2];
    f32x4 b = ((const f32x4*)src)[i * 2 + 1];
    u16x8 o;
#pragma unroll
    for (int j = 0; j < 4; ++j) o[j] = f2bf(a[j]);
#pragma unroll
    for (int j = 0; j < 4; ++j) o[4 + j] = f2bf(b[j]);
    ((u16x8*)dst)[i] = o;
}

// ---------------- k0b: rope tables ----------------
__global__ __launch_bounds__(256) void rope_tab_k(float2* __restrict__ tab) {
    int idx = blockIdx.x * 256 + threadIdx.x;   // 65536 = T*32
    int t = idx >> 5, j = idx & 31;
    float inv = __builtin_exp2f(-0.41524101186092f * (float)j);  // 10000^(-j/32)
    float s_, c_;
    sincosf((float)t * inv, &s_, &c_);
    tab[idx] = make_float2(c_, s_);
}

// ---------------- k1: QKV GEMM + RoPE (MFMA, bf16 inputs) ----------------
// grid (24, 32): n0 = bx*128 (0..3071), m0 = by*128 (0..4095)
__global__ __launch_bounds__(256) void qkv_rope_k(const u16* __restrict__ xb, const u16* __restrict__ Wab,
                                                  const float* __restrict__ bias,
                                                  const float2* __restrict__ tab,
                                                  u16* __restrict__ qb, u16* __restrict__ kb,
                                                  u16* __restrict__ vt) {
    __shared__ u16 smem[2 * 128 * 72];
    u16* As = smem;
    u16* Bs = smem + 128 * 72;
    int tid = threadIdx.x;
    int n0 = blockIdx.x * 128, m0 = blockIdx.y * 128;
    int w = tid >> 6, lane = tid & 63, lr = lane & 15, quad = lane >> 4;
    int wr = w >> 1, wc = w & 1;
    f32x4 acc[4][4] = {};
    for (int kt = 0; kt < C_EMB; kt += 64) {
#pragma unroll
        for (int it = 0; it < 4; ++it) {
            int idx = it * 256 + tid;
            int row = idx >> 3, c8 = (idx & 7) << 3;
            *(s16x8*)&As[row * 72 + c8] = *(const s16x8*)(xb + (size_t)(m0 + row) * C_EMB + kt + c8);
            *(s16x8*)&Bs[row * 72 + c8] = *(const s16x8*)(Wab + (size_t)(n0 + row) * C_EMB + kt + c8);
        }
        __syncthreads();
#pragma unroll
        for (int ks = 0; ks < 64; ks += 32) {
            s16x8 af[4], bf[4];
#pragma unroll
            for (int i = 0; i < 4; ++i)
                af[i] = *(const s16x8*)&As[(wr * 64 + i * 16 + lr) * 72 + ks + quad * 8];
#pragma unroll
            for (int j = 0; j < 4; ++j)
                bf[j] = *(const s16x8*)&Bs[(wc * 64 + j * 16 + lr) * 72 + ks + quad * 8];
#pragma unroll
            for (int i = 0; i < 4; ++i)
#pragma unroll
                for (int j = 0; j < 4; ++j) acc[i][j] = MFMA16(af[i], bf[j], acc[i][j]);
        }
        __syncthreads();
    }
    int sec = n0 >> 10;                       // 0=q 1=k 2=v (blocks never straddle)
    float bv[4];
#pragma unroll
    for (int j = 0; j < 4; ++j) bv[j] = bias[n0 + wc * 64 + j * 16 + lr];

    int h0 = (n0 & 1023) >> 6;
    int b = m0 >> 11, tbase = m0 & 2047;
    if (sec == 2) {
        // C tile (+bias) -> LDS [d][m] (136-padded) -> coalesced 16B
        // transposed stores to vt[((b*16+h)*64+d)*2048 + t].
        u16* Ct = smem;                        // 128 x 136 u16 = 34816 B
#pragma unroll
        for (int i = 0; i < 4; ++i)
#pragma unroll
            for (int j = 0; j < 4; ++j) {
                f32x4 vv;
#pragma unroll
                for (int r = 0; r < 4; ++r) vv[r] = acc[i][j][r] + bv[j];
                int d = wc * 64 + j * 16 + lr;
                int m4 = wr * 64 + i * 16 + quad * 4;
                *(u16x4*)&Ct[d * 136 + m4] = pack4(vv);
            }
        __syncthreads();
        size_t hb = (size_t)(b * NH);
#pragma unroll
        for (int p = 0; p < 8; ++p) {
            int idx = p * 256 + tid;
            int d = idx >> 4, mc = (idx & 15) << 3;
            s16x8 vdat = *(const s16x8*)&Ct[d * 136 + mc];
            int h = h0 + (d >> 6), dd = d & 63;
            *(s16x8*)(vt + ((hb + h) * HD + dd) * T_SEQ + tbase + mc) = vdat;
        }
    } else {
        // q/k: RoPE in-register, stage [m][n] in LDS, coalesced b128 stores.
        u16* dst = (sec == 0) ? qb : kb;
        // fold 1/sqrt(D) AND log2(e) into q so flash softmax is native base-2:
        // 0.125 * 1.4426950408889634 = 0.18033688011112043
        float qs = (sec == 0) ? 0.18033688011112043f : 1.0f;
        u16* Ct = smem;                        // 128 x 136 u16
#pragma unroll
        for (int i = 0; i < 4; ++i)
#pragma unroll
            for (int r = 0; r < 4; ++r) {
                int mrow = wr * 64 + i * 16 + quad * 4 + r;
                int t = (m0 + mrow) & 2047;
#pragma unroll
                for (int j = 0; j < 2; ++j) {
                    int d1 = j * 16 + lr;                 // 0..31; partner +32 in tile j+2
                    float2 cs = tab[t * 32 + d1];
                    float v1 = acc[i][j][r] + bv[j];
                    float v2 = acc[i][j + 2][r] + bv[j + 2];
                    int n1 = wc * 64 + j * 16 + lr;
                    Ct[mrow * 136 + n1]      = f2bf((v1 * cs.x - v2 * cs.y) * qs);
                    Ct[mrow * 136 + n1 + 32] = f2bf((v2 * cs.x + v1 * cs.y) * qs);
                }
            }
        __syncthreads();
#pragma unroll
        for (int p = 0; p < 8; ++p) {
            int idx = p * 256 + tid;              // 128 rows x 16 chunks of 8 u16
            int mrow = idx >> 4, c = idx & 15;
            s16x8 vdat = *(const s16x8*)&Ct[mrow * 136 + c * 8];
            int h = h0 + (c >> 3), dd = (c & 7) << 3;
            *(s16x8*)(dst + ((size_t)(b * NH + h) * T_SEQ + tbase + mrow) * HD + dd) = vdat;
        }
    }
}

// ---------------- k2: flash attention (MFMA, S^T/O^T form) ----------------
// grid (16, 32): 128-row Q tile, bh. Wave w owns strips at rows w*16 and
// 112-w*16 (complementary: every wave does exactly 4qt+3 strip-tiles).
// S^T tile: elem (k' = k0+tc*16+quad*4+r, q = rbase+lr) — lane owns q-row lr.
// Double-buffered K/V LDS: global loads for tile kt+1 issued at top of iter
// kt, ds_write to the other buffer after compute, ONE barrier per iter.
__global__ __launch_bounds__(256) void flash_k(const u16* __restrict__ qb, const u16* __restrict__ kb,
                                               const u16* __restrict__ vt, u16* __restrict__ yab) {
    __shared__ u16 Ks[2][64 * 72];
    __shared__ u16 Vs[2][64 * 72];
    __shared__ u16 Ps[4][32 * 72];           // [wave][strip-slot 32][k' 64 pad 72]
    int tid = threadIdx.x;
    int bx = blockIdx.x, by = blockIdx.y;
    int qt = (by < 16) ? (15 - bx) : bx;      // complementary pairing for balance
    int bh = by;
    int w = tid >> 6, lane = tid & 63, lr = lane & 15, quad = lane >> 4;
    int q0 = qt * 128;
    const u16* qh = qb + (size_t)bh * T_SEQ * HD;
    const u16* kh = kb + (size_t)bh * T_SEQ * HD;
    const u16* vh = vt + (size_t)bh * HD * T_SEQ;

    int rb[2];                                // complementary strip rows
    rb[0] = q0 + w * 16;
    rb[1] = q0 + 112 - w * 16;

    s16x8 aq[2][2];                           // B-frag of Q (n=q-row=lr, k=d)
#pragma unroll
    for (int s = 0; s < 2; ++s)
#pragma unroll
        for (int ks = 0; ks < 2; ++ks)
            aq[s][ks] = *(const s16x8*)(qh + (size_t)(rb[s] + lr) * HD + ks * 32 + quad * 8);

    int srow = tid >> 3, sc8 = (tid & 7) << 3;   // staging coords (rows 0..31, +32)

    float m_i[2] = {-1e30f, -1e30f}, l_i[2] = {0.f, 0.f};
    f32x4 oacc[2][4] = {};                    // O^T: elem (d=tn*16+quad*4+r, q=lr)

    int ktmax = 2 * qt + 1;
    {   // prologue: stage tile 0 into buffer 0
        s16x8 kr0 = *(const s16x8*)(kh + (size_t)srow * HD + sc8);
        s16x8 kr1 = *(const s16x8*)(kh + (size_t)(srow + 32) * HD + sc8);
        s16x8 vr0 = *(const s16x8*)(vh + (size_t)srow * T_SEQ + sc8);
        s16x8 vr1 = *(const s16x8*)(vh + (size_t)(srow + 32) * T_SEQ + sc8);
        *(s16x8*)&Ks[0][srow * 72 + sc8] = kr0;
        *(s16x8*)&Ks[0][(srow + 32) * 72 + sc8] = kr1;
        *(s16x8*)&Vs[0][srow * 72 + sc8] = vr0;
        *(s16x8*)&Vs[0][(srow + 32) * 72 + sc8] = vr1;
    }
    __syncthreads();

    for (int kt = 0; kt <= ktmax; ++kt) {
        int cur = kt & 1;
        int k0 = kt * 64;
        bool pf = kt < ktmax;
        s16x8 kr0, kr1, vr0, vr1;             // next-tile prefetch registers
        if (pf) {
            int kn = k0 + 64;
            kr0 = *(const s16x8*)(kh + (size_t)(kn + srow) * HD + sc8);
            kr1 = *(const s16x8*)(kh + (size_t)(kn + srow + 32) * HD + sc8);
            vr0 = *(const s16x8*)(vh + (size_t)srow * T_SEQ + kn + sc8);
            vr1 = *(const s16x8*)(vh + (size_t)(srow + 32) * T_SEQ + kn + sc8);
        }
        const u16* Kc = Ks[cur];
        const u16* Vc = Vs[cur];
        s16x8 ak[2][4], av[2][4];             // K frag (m=k-row=lr) / V frag (m=d=lr)
#pragma unroll
        for (int ks = 0; ks < 2; ++ks)
#pragma unroll
            for (int tc = 0; tc < 4; ++tc) {
                ak[ks][tc] = *(const s16x8*)&Kc[(tc * 16 + lr) * 72 + ks * 32 + quad * 8];
                av[ks][tc] = *(const s16x8*)&Vc[(tc * 16 + lr) * 72 + ks * 32 + quad * 8];
            }

#pragma unroll
        for (int s = 0; s < 2; ++s) {
            int rbase = rb[s];
            if (k0 > rbase + 15) continue;     // strip fully above diagonal
            f32x4 sacc[4] = {};
#pragma unroll
            for (int ks = 0; ks < 2; ++ks)
#pragma unroll
                for (int tc = 0; tc < 4; ++tc) sacc[tc] = MFMA16(ak[ks][tc], aq[s][ks], sacc[tc]);
            if (k0 + 63 > rbase) {
#pragma unroll
                for (int tc = 0; tc < 4; ++tc)
#pragma unroll
                    for (int r = 0; r < 4; ++r)
                        if (k0 + tc * 16 + quad * 4 + r > rbase + lr) sacc[tc][r] = -1e30f;
            }
            // per-lane softmax (base-2: log2e folded into q) for q-row rbase+lr
            f32x4 mv = sacc[0];
#pragma unroll
            for (int tc = 1; tc < 4; ++tc)
#pragma unroll
                for (int r = 0; r < 4; ++r) mv[r] = fmaxf(mv[r], sacc[tc][r]);
            float mx = fmaxf(fmaxf(mv[0], mv[1]), fmaxf(mv[2], mv[3]));
            mx = fmaxf(mx, __shfl_xor(mx, 16, 64));
            mx = fmaxf(mx, __shfl_xor(mx, 32, 64));
            float mo = m_i[s];
            bool need = !__all(mx <= mo + 8.0f);   // defer-max (T13, THR=8)
            float alpha = 1.0f;
            if (need) {
                float mn = fmaxf(mo, mx);
                alpha = __builtin_exp2f(mo - mn);
                m_i[s] = mn;
                l_i[s] *= alpha;
            }
            float mnow = m_i[s];
            f32x4 rv = {0.f, 0.f, 0.f, 0.f};
#pragma unroll
            for (int tc = 0; tc < 4; ++tc)
#pragma unroll
                for (int r = 0; r < 4; ++r) {
                    float p = __builtin_exp2f(sacc[tc][r] - mnow);
                    sacc[tc][r] = p;
                    rv[r] += p;
                }
            float rs = (rv[0] + rv[1]) + (rv[2] + rv[3]);
            rs += __shfl_xor(rs, 16, 64);
            rs += __shfl_xor(rs, 32, 64);
            l_i[s] += rs;
            // P^T -> LDS [slot][k'] (u16x4 writes); rescale fills write->read gap
#pragma unroll
            for (int tc = 0; tc < 4; ++tc)
                *(u16x4*)&Ps[w][(s * 16 + lr) * 72 + tc * 16 + quad * 4] = pack4(sacc[tc]);
            if (need) {
#pragma unroll
                for (int tn = 0; tn < 4; ++tn)
#pragma unroll
                    for (int r = 0; r < 4; ++r) oacc[s][tn][r] *= alpha;
            }
#pragma unroll
            for (int ks = 0; ks < 2; ++ks) {
                s16x8 ap = *(const s16x8*)&Ps[w][(s * 16 + lr) * 72 + ks * 32 + quad * 8];
#pragma unroll
                for (int tn = 0; tn < 4; ++tn) oacc[s][tn] = MFMA16(av[ks][tn], ap, oacc[s][tn]);
            }
        }
        if (pf) {                              // write prefetched tile to other buffer
            int nx = cur ^ 1;
            *(s16x8*)&Ks[nx][srow * 72 + sc8] = kr0;
            *(s16x8*)&Ks[nx][(srow + 32) * 72 + sc8] = kr1;
            *(s16x8*)&Vs[nx][srow * 72 + sc8] = vr0;
            *(s16x8*)&Vs[nx][(srow + 32) * 72 + sc8] = vr1;
        }
        __syncthreads();                       // single barrier per k-tile
    }
    int b = bh >> 4, hh = bh & 15;
#pragma unroll
    for (int s = 0; s < 2; ++s) {
        float inv = 1.f / l_i[s];
        int t = rb[s] + lr;
        size_t base = ((size_t)b * T_SEQ + t) * C_EMB + hh * HD;
#pragma unroll
        for (int tn = 0; tn < 4; ++tn) {
            f32x4 vv;
#pragma unroll
            for (int r = 0; r < 4; ++r) vv[r] = oacc[s][tn][r] * inv;
            *(u16x4*)(yab + base + tn * 16 + quad * 4) = pack4(vv);
        }
    }
}

// ---------------- k3: output projection (MFMA, bf16 inputs) ----------------
// grid (8, 32): n0 = bx*128 (0..1023), m0 = by*128
__global__ __launch_bounds__(256) void proj_k(const u16* __restrict__ ya, const u16* __restrict__ Wpb,
                                              const float* __restrict__ bias, float* __restrict__ out) {
    __shared__ u16 As[128 * 72];
    __shared__ u16 Bs[128 * 72];
    int tid = threadIdx.x;
    int n0 = blockIdx.x * 128, m0 = blockIdx.y * 128;
    int w = tid >> 6, lane = tid & 63, lr = lane & 15, quad = lane >> 4;
    int wr = w >> 1, wc = w & 1;
    f32x4 acc[4][4] = {};
    for (int kt = 0; kt < C_EMB; kt += 64) {
#pragma unroll
        for (int it = 0; it < 4; ++it) {
            int idx = it * 256 + tid;
            int row = idx >> 3, c8 = (idx & 7) << 3;
            *(s16x8*)&As[row * 72 + c8] = *(const s16x8*)(ya + (size_t)(m0 + row) * C_EMB + kt + c8);
            *(s16x8*)&Bs[row * 72 + c8] = *(const s16x8*)(Wpb + (size_t)(n0 + row) * C_EMB + kt + c8);
        }
        __syncthreads();
#pragma unroll
        for (int ks = 0; ks < 64; ks += 32) {
            s16x8 af[4], bf[4];
#pragma unroll
            for (int i = 0; i < 4; ++i)
                af[i] = *(const s16x8*)&As[(wr * 64 + i * 16 + lr) * 72 + ks + quad * 8];
#pragma unroll
            for (int j = 0; j < 4; ++j)
                bf[j] = *(const s16x8*)&Bs[(wc * 64 + j * 16 + lr) * 72 + ks + quad * 8];
#pragma unroll
            for (int i = 0; i < 4; ++i)
#pragma unroll
                for (int j = 0; j < 4; ++j) acc[i][j] = MFMA16(af[i], bf[j], acc[i][j]);
        }
        __syncthreads();
    }
    float bv[4];
#pragma unroll
    for (int j = 0; j < 4; ++j) bv[j] = bias[n0 + wc * 64 + j * 16 + lr];
#pragma unroll
    for (int i = 0; i < 4; ++i)
#pragma unroll
        for (int r = 0; r < 4; ++r) {
            int m = m0 + wr * 64 + i * 16 + quad * 4 + r;
#pragma unroll
            for (int j = 0; j < 4; ++j)
                out[(size_t)m * C_EMB + n0 + wc * 64 + j * 16 + lr] = acc[i][j][r] + bv[j];
        }
}

extern "C" void kernel_launch(void* const* d_in, const int* in_sizes, int n_in,
                              void* d_out, int out_size, void* d_ws, size_t ws_size,
                              hipStream_t stream) {
    // Inputs resolved BY ELEMENT COUNT (unique): x 4194304, W_attn 3145728,
    // b_attn 3072, W_proj 1048576, b_proj 1024. All fp32.
    const float *x = nullptr, *Wa = nullptr, *ba = nullptr, *Wp = nullptr, *bp = nullptr;
    for (int i = 0; i < n_in; ++i) {
        switch (in_sizes[i]) {
            case 4194304: x  = (const float*)d_in[i]; break;
            case 3145728: Wa = (const float*)d_in[i]; break;
            case 3072:    ba = (const float*)d_in[i]; break;
            case 1048576: Wp = (const float*)d_in[i]; break;
            case 1024:    bp = (const float*)d_in[i]; break;
            default: break;
        }
    }
    float* out = (float*)d_out;

    char* ws = (char*)d_ws;
    u16* qb     = (u16*)(ws);                    //  0.. 8 MiB  bf16 [B,H,T,D] (q*0.125*log2e)
    u16* kb     = (u16*)(ws + 8388608);          //  8..16 MiB  bf16 [B,H,T,D]
    u16* vt     = (u16*)(ws + 16777216);         // 16..24 MiB  bf16 [B,H,D,T]
    u16* yab    = (u16*)(ws + 25165824);         // 24..32 MiB  bf16 [B,T,C]
    float2* tab = (float2*)(ws + 33554432);      // 32..32.5 MiB
    u16* xb     = (u16*)(ws + 35651584);         // 34..42 MiB  bf16 [4096,1024]
    u16* Wab    = (u16*)(ws + 44040192);         // 42..48 MiB  bf16 [3072,1024]
    u16* Wpb    = (u16*)(ws + 50331648);         // 48..50 MiB  bf16 [1024,1024]

    conv_k<<<2048, 256, 0, stream>>>(x, xb, 524288);
    conv_k<<<1536, 256, 0, stream>>>(Wa, Wab, 393216);
    conv_k<<<512, 256, 0, stream>>>(Wp, Wpb, 131072);
    rope_tab_k<<<256, 256, 0, stream>>>(tab);
    qkv_rope_k<<<dim3(24, 32), 256, 0, stream>>>(xb, Wab, ba, tab, qb, kb, vt);
    flash_k<<<dim3(16, 32), 256, 0, stream>>>(qb, kb, vt, yab);
    proj_k<<<dim3(8, 32), 256, 0, stream>>>(yab, Wpb, bp, out);
}

// Round 2
// 212.426 us; speedup vs baseline: 1.0512x; 1.0473x over previous
//
#include <hip/hip_runtime.h>

// B=2, T=2048, C=1024, H=16, D=64. Inputs fp32, OUTPUT fp32.
// Round 14: flash_k widened to 512 threads / 8 waves, ONE 16-row strip per
// wave (same 128-row Q tile, grid 16x32). LDS unchanged (55.3KB, 2 blocks/CU)
// -> occupancy doubles to 16 waves/CU and the whole 512-block grid is
// co-resident (no dispatch tail; complementary qt pairing balances per-CU
// work). Keeps R13's double-buffered K/V with async-STAGE split (one barrier
// per k-tile), base-2 softmax, defer-max (THR=8). Rest = round 13.
// MFMA 16x16x32_bf16 layouts (HW-verified): A: m=lane&15,k=quad*8+j;
// B: k=quad*8+j,n=lane&15; C/D: col=lane&15,row=quad*4+reg.

typedef unsigned short u16;
typedef u16 u16x4 __attribute__((ext_vector_type(4)));
typedef u16 u16x8 __attribute__((ext_vector_type(8)));
typedef short s16x8 __attribute__((ext_vector_type(8)));
typedef float f32x4 __attribute__((ext_vector_type(4)));

#define T_SEQ 2048
#define C_EMB 1024
#define NH 16
#define HD 64

#define MFMA16(a, b, c) __builtin_amdgcn_mfma_f32_16x16x32_bf16(a, b, c, 0, 0, 0)

__device__ __forceinline__ u16 f2bf(float f) {
    union { float f; unsigned int i; } x; x.f = f;
    unsigned int r = x.i + 0x7fffu + ((x.i >> 16) & 1u);
    return (u16)(r >> 16);
}
__device__ __forceinline__ u16x4 pack4(f32x4 v) {
    u16x4 o;
#pragma unroll
    for (int j = 0; j < 4; ++j) o[j] = f2bf(v[j]);
    return o;
}

// ---------------- k0a: fp32 -> bf16 convert ----------------
__global__ __launch_bounds__(256) void conv_k(const float* __restrict__ src, u16* __restrict__ dst, int n8) {
    int i = blockIdx.x * 256 + threadIdx.x;
    if (i >= n8) return;
    f32x4 a = ((const f32x4*)src)[i * 2];
    f32x4 b = ((const f32x4*)src)[i * 2 + 1];
    u16x8 o;
#pragma unroll
    for (int j = 0; j < 4; ++j) o[j] = f2bf(a[j]);
#pragma unroll
    for (int j = 0; j < 4; ++j) o[4 + j] = f2bf(b[j]);
    ((u16x8*)dst)[i] = o;
}

// ---------------- k0b: rope tables ----------------
__global__ __launch_bounds__(256) void rope_tab_k(float2* __restrict__ tab) {
    int idx = blockIdx.x * 256 + threadIdx.x;   // 65536 = T*32
    int t = idx >> 5, j = idx & 31;
    float inv = __builtin_exp2f(-0.41524101186092f * (float)j);  // 10000^(-j/32)
    float s_, c_;
    sincosf((float)t * inv, &s_, &c_);
    tab[idx] = make_float2(c_, s_);
}

// ---------------- k1: QKV GEMM + RoPE (MFMA, bf16 inputs) ----------------
// grid (24, 32): n0 = bx*128 (0..3071), m0 = by*128 (0..4095)
__global__ __launch_bounds__(256) void qkv_rope_k(const u16* __restrict__ xb, const u16* __restrict__ Wab,
                                                  const float* __restrict__ bias,
                                                  const float2* __restrict__ tab,
                                                  u16* __restrict__ qb, u16* __restrict__ kb,
                                                  u16* __restrict__ vt) {
    __shared__ u16 smem[2 * 128 * 72];
    u16* As = smem;
    u16* Bs = smem + 128 * 72;
    int tid = threadIdx.x;
    int n0 = blockIdx.x * 128, m0 = blockIdx.y * 128;
    int w = tid >> 6, lane = tid & 63, lr = lane & 15, quad = lane >> 4;
    int wr = w >> 1, wc = w & 1;
    f32x4 acc[4][4] = {};
    for (int kt = 0; kt < C_EMB; kt += 64) {
#pragma unroll
        for (int it = 0; it < 4; ++it) {
            int idx = it * 256 + tid;
            int row = idx >> 3, c8 = (idx & 7) << 3;
            *(s16x8*)&As[row * 72 + c8] = *(const s16x8*)(xb + (size_t)(m0 + row) * C_EMB + kt + c8);
            *(s16x8*)&Bs[row * 72 + c8] = *(const s16x8*)(Wab + (size_t)(n0 + row) * C_EMB + kt + c8);
        }
        __syncthreads();
#pragma unroll
        for (int ks = 0; ks < 64; ks += 32) {
            s16x8 af[4], bf[4];
#pragma unroll
            for (int i = 0; i < 4; ++i)
                af[i] = *(const s16x8*)&As[(wr * 64 + i * 16 + lr) * 72 + ks + quad * 8];
#pragma unroll
            for (int j = 0; j < 4; ++j)
                bf[j] = *(const s16x8*)&Bs[(wc * 64 + j * 16 + lr) * 72 + ks + quad * 8];
#pragma unroll
            for (int i = 0; i < 4; ++i)
#pragma unroll
                for (int j = 0; j < 4; ++j) acc[i][j] = MFMA16(af[i], bf[j], acc[i][j]);
        }
        __syncthreads();
    }
    int sec = n0 >> 10;                       // 0=q 1=k 2=v (blocks never straddle)
    float bv[4];
#pragma unroll
    for (int j = 0; j < 4; ++j) bv[j] = bias[n0 + wc * 64 + j * 16 + lr];

    int h0 = (n0 & 1023) >> 6;
    int b = m0 >> 11, tbase = m0 & 2047;
    if (sec == 2) {
        // C tile (+bias) -> LDS [d][m] (136-padded) -> coalesced 16B
        // transposed stores to vt[((b*16+h)*64+d)*2048 + t].
        u16* Ct = smem;                        // 128 x 136 u16 = 34816 B
#pragma unroll
        for (int i = 0; i < 4; ++i)
#pragma unroll
            for (int j = 0; j < 4; ++j) {
                f32x4 vv;
#pragma unroll
                for (int r = 0; r < 4; ++r) vv[r] = acc[i][j][r] + bv[j];
                int d = wc * 64 + j * 16 + lr;
                int m4 = wr * 64 + i * 16 + quad * 4;
                *(u16x4*)&Ct[d * 136 + m4] = pack4(vv);
            }
        __syncthreads();
        size_t hb = (size_t)(b * NH);
#pragma unroll
        for (int p = 0; p < 8; ++p) {
            int idx = p * 256 + tid;
            int d = idx >> 4, mc = (idx & 15) << 3;
            s16x8 vdat = *(const s16x8*)&Ct[d * 136 + mc];
            int h = h0 + (d >> 6), dd = d & 63;
            *(s16x8*)(vt + ((hb + h) * HD + dd) * T_SEQ + tbase + mc) = vdat;
        }
    } else {
        // q/k: RoPE in-register, stage [m][n] in LDS, coalesced b128 stores.
        u16* dst = (sec == 0) ? qb : kb;
        // fold 1/sqrt(D) AND log2(e) into q so flash softmax is native base-2:
        // 0.125 * 1.4426950408889634 = 0.18033688011112043
        float qs = (sec == 0) ? 0.18033688011112043f : 1.0f;
        u16* Ct = smem;                        // 128 x 136 u16
#pragma unroll
        for (int i = 0; i < 4; ++i)
#pragma unroll
            for (int r = 0; r < 4; ++r) {
                int mrow = wr * 64 + i * 16 + quad * 4 + r;
                int t = (m0 + mrow) & 2047;
#pragma unroll
                for (int j = 0; j < 2; ++j) {
                    int d1 = j * 16 + lr;                 // 0..31; partner +32 in tile j+2
                    float2 cs = tab[t * 32 + d1];
                    float v1 = acc[i][j][r] + bv[j];
                    float v2 = acc[i][j + 2][r] + bv[j + 2];
                    int n1 = wc * 64 + j * 16 + lr;
                    Ct[mrow * 136 + n1]      = f2bf((v1 * cs.x - v2 * cs.y) * qs);
                    Ct[mrow * 136 + n1 + 32] = f2bf((v2 * cs.x + v1 * cs.y) * qs);
                }
            }
        __syncthreads();
#pragma unroll
        for (int p = 0; p < 8; ++p) {
            int idx = p * 256 + tid;              // 128 rows x 16 chunks of 8 u16
            int mrow = idx >> 4, c = idx & 15;
            s16x8 vdat = *(const s16x8*)&Ct[mrow * 136 + c * 8];
            int h = h0 + (c >> 3), dd = (c & 7) << 3;
            *(s16x8*)(dst + ((size_t)(b * NH + h) * T_SEQ + tbase + mrow) * HD + dd) = vdat;
        }
    }
}

// ---------------- k2: flash attention (MFMA, S^T/O^T form) ----------------
// grid (16, 32), 512 threads / 8 waves. 128-row Q tile; wave w owns the ONE
// strip at rows [q0+16w, +16). All 512 blocks co-resident (2/CU, 16 waves/CU);
// complementary qt pairing (by<16 vs >=16) balances per-CU work.
// S^T tile: elem (k' = k0+tc*16+quad*4+r, q = rbase+lr) — lane owns q-row lr.
// Double-buffered K/V LDS: global loads for tile kt+1 issued at top of iter
// kt, ds_write to the other buffer after compute, ONE barrier per iter.
__global__ __launch_bounds__(512, 4) void flash_k(const u16* __restrict__ qb, const u16* __restrict__ kb,
                                                  const u16* __restrict__ vt, u16* __restrict__ yab) {
    __shared__ u16 Ks[2][64 * 72];
    __shared__ u16 Vs[2][64 * 72];
    __shared__ u16 Ps[8][16 * 72];           // [wave][q-row 16][k' 64 pad 72]
    int tid = threadIdx.x;
    int bx = blockIdx.x, by = blockIdx.y;
    int qt = (by < 16) ? (15 - bx) : bx;      // complementary pairing for balance
    int bh = by;
    int w = tid >> 6, lane = tid & 63, lr = lane & 15, quad = lane >> 4;
    int q0 = qt * 128;
    const u16* qh = qb + (size_t)bh * T_SEQ * HD;
    const u16* kh = kb + (size_t)bh * T_SEQ * HD;
    const u16* vh = vt + (size_t)bh * HD * T_SEQ;

    int rbase = q0 + w * 16;                  // this wave's strip

    s16x8 aq[2];                              // B-frag of Q (n=q-row=lr, k=d)
#pragma unroll
    for (int ks = 0; ks < 2; ++ks)
        aq[ks] = *(const s16x8*)(qh + (size_t)(rbase + lr) * HD + ks * 32 + quad * 8);

    int srow = tid >> 3, sc8 = (tid & 7) << 3;   // staging coords: rows 0..63

    float m_i = -1e30f, l_i = 0.f;
    f32x4 oacc[4] = {};                       // O^T: elem (d=tn*16+quad*4+r, q=lr)

    int ktmax = 2 * qt + 1;
    {   // prologue: stage tile 0 into buffer 0 (1 K-row + 1 V-row per thread)
        s16x8 kr0 = *(const s16x8*)(kh + (size_t)srow * HD + sc8);
        s16x8 vr0 = *(const s16x8*)(vh + (size_t)srow * T_SEQ + sc8);
        *(s16x8*)&Ks[0][srow * 72 + sc8] = kr0;
        *(s16x8*)&Vs[0][srow * 72 + sc8] = vr0;
    }
    __syncthreads();

    for (int kt = 0; kt <= ktmax; ++kt) {
        int cur = kt & 1;
        int k0 = kt * 64;
        bool pf = kt < ktmax;
        s16x8 kr0, vr0;                       // next-tile prefetch registers
        if (pf) {
            int kn = k0 + 64;
            kr0 = *(const s16x8*)(kh + (size_t)(kn + srow) * HD + sc8);
            vr0 = *(const s16x8*)(vh + (size_t)srow * T_SEQ + kn + sc8);
        }
        const u16* Kc = Ks[cur];
        const u16* Vc = Vs[cur];

        if (k0 <= rbase + 15) {               // strip not fully above diagonal
            s16x8 ak[2][4], av[2][4];         // K frag (m=k-row=lr) / V frag (m=d=lr)
#pragma unroll
            for (int ks = 0; ks < 2; ++ks)
#pragma unroll
                for (int tc = 0; tc < 4; ++tc) {
                    ak[ks][tc] = *(const s16x8*)&Kc[(tc * 16 + lr) * 72 + ks * 32 + quad * 8];
                    av[ks][tc] = *(const s16x8*)&Vc[(tc * 16 + lr) * 72 + ks * 32 + quad * 8];
                }
            f32x4 sacc[4] = {};
#pragma unroll
            for (int ks = 0; ks < 2; ++ks)
#pragma unroll
                for (int tc = 0; tc < 4; ++tc) sacc[tc] = MFMA16(ak[ks][tc], aq[ks], sacc[tc]);
            if (k0 + 63 > rbase) {
#pragma unroll
                for (int tc = 0; tc < 4; ++tc)
#pragma unroll
                    for (int r = 0; r < 4; ++r)
                        if (k0 + tc * 16 + quad * 4 + r > rbase + lr) sacc[tc][r] = -1e30f;
            }
            // per-lane softmax (base-2: log2e folded into q) for q-row rbase+lr
            f32x4 mv = sacc[0];
#pragma unroll
            for (int tc = 1; tc < 4; ++tc)
#pragma unroll
                for (int r = 0; r < 4; ++r) mv[r] = fmaxf(mv[r], sacc[tc][r]);
            float mx = fmaxf(fmaxf(mv[0], mv[1]), fmaxf(mv[2], mv[3]));
            mx = fmaxf(mx, __shfl_xor(mx, 16, 64));
            mx = fmaxf(mx, __shfl_xor(mx, 32, 64));
            float mo = m_i;
            bool need = !__all(mx <= mo + 8.0f);   // defer-max (T13, THR=8)
            float alpha = 1.0f;
            if (need) {
                float mn = fmaxf(mo, mx);
                alpha = __builtin_exp2f(mo - mn);
                m_i = mn;
                l_i *= alpha;
            }
            float mnow = m_i;
            f32x4 rv = {0.f, 0.f, 0.f, 0.f};
#pragma unroll
            for (int tc = 0; tc < 4; ++tc)
#pragma unroll
                for (int r = 0; r < 4; ++r) {
                    float p = __builtin_exp2f(sacc[tc][r] - mnow);
                    sacc[tc][r] = p;
                    rv[r] += p;
                }
            float rs = (rv[0] + rv[1]) + (rv[2] + rv[3]);
            rs += __shfl_xor(rs, 16, 64);
            rs += __shfl_xor(rs, 32, 64);
            l_i += rs;
            // P^T -> LDS [q][k'] (u16x4 writes); rescale fills write->read gap
#pragma unroll
            for (int tc = 0; tc < 4; ++tc)
                *(u16x4*)&Ps[w][lr * 72 + tc * 16 + quad * 4] = pack4(sacc[tc]);
            if (need) {
#pragma unroll
                for (int tn = 0; tn < 4; ++tn)
#pragma unroll
                    for (int r = 0; r < 4; ++r) oacc[tn][r] *= alpha;
            }
#pragma unroll
            for (int ks = 0; ks < 2; ++ks) {
                s16x8 ap = *(const s16x8*)&Ps[w][lr * 72 + ks * 32 + quad * 8];
#pragma unroll
                for (int tn = 0; tn < 4; ++tn) oacc[tn] = MFMA16(av[ks][tn], ap, oacc[tn]);
            }
        }
        if (pf) {                              // write prefetched tile to other buffer
            int nx = cur ^ 1;
            *(s16x8*)&Ks[nx][srow * 72 + sc8] = kr0;
            *(s16x8*)&Vs[nx][srow * 72 + sc8] = vr0;
        }
        __syncthreads();                       // single barrier per k-tile
    }
    int b = bh >> 4, hh = bh & 15;
    {
        float inv = 1.f / l_i;
        int t = rbase + lr;
        size_t base = ((size_t)b * T_SEQ + t) * C_EMB + hh * HD;
#pragma unroll
        for (int tn = 0; tn < 4; ++tn) {
            f32x4 vv;
#pragma unroll
            for (int r = 0; r < 4; ++r) vv[r] = oacc[tn][r] * inv;
            *(u16x4*)(yab + base + tn * 16 + quad * 4) = pack4(vv);
        }
    }
}

// ---------------- k3: output projection (MFMA, bf16 inputs) ----------------
// grid (8, 32): n0 = bx*128 (0..1023), m0 = by*128
__global__ __launch_bounds__(256) void proj_k(const u16* __restrict__ ya, const u16* __restrict__ Wpb,
                                              const float* __restrict__ bias, float* __restrict__ out) {
    __shared__ u16 As[128 * 72];
    __shared__ u16 Bs[128 * 72];
    int tid = threadIdx.x;
    int n0 = blockIdx.x * 128, m0 = blockIdx.y * 128;
    int w = tid >> 6, lane = tid & 63, lr = lane & 15, quad = lane >> 4;
    int wr = w >> 1, wc = w & 1;
    f32x4 acc[4][4] = {};
    for (int kt = 0; kt < C_EMB; kt += 64) {
#pragma unroll
        for (int it = 0; it < 4; ++it) {
            int idx = it * 256 + tid;
            int row = idx >> 3, c8 = (idx & 7) << 3;
            *(s16x8*)&As[row * 72 + c8] = *(const s16x8*)(ya + (size_t)(m0 + row) * C_EMB + kt + c8);
            *(s16x8*)&Bs[row * 72 + c8] = *(const s16x8*)(Wpb + (size_t)(n0 + row) * C_EMB + kt + c8);
        }
        __syncthreads();
#pragma unroll
        for (int ks = 0; ks < 64; ks += 32) {
            s16x8 af[4], bf[4];
#pragma unroll
            for (int i = 0; i < 4; ++i)
                af[i] = *(const s16x8*)&As[(wr * 64 + i * 16 + lr) * 72 + ks + quad * 8];
#pragma unroll
            for (int j = 0; j < 4; ++j)
                bf[j] = *(const s16x8*)&Bs[(wc * 64 + j * 16 + lr) * 72 + ks + quad * 8];
#pragma unroll
            for (int i = 0; i < 4; ++i)
#pragma unroll
                for (int j = 0; j < 4; ++j) acc[i][j] = MFMA16(af[i], bf[j], acc[i][j]);
        }
        __syncthreads();
    }
    float bv[4];
#pragma unroll
    for (int j = 0; j < 4; ++j) bv[j] = bias[n0 + wc * 64 + j * 16 + lr];
#pragma unroll
    for (int i = 0; i < 4; ++i)
#pragma unroll
        for (int r = 0; r < 4; ++r) {
            int m = m0 + wr * 64 + i * 16 + quad * 4 + r;
#pragma unroll
            for (int j = 0; j < 4; ++j)
                out[(size_t)m * C_EMB + n0 + wc * 64 + j * 16 + lr] = acc[i][j][r] + bv[j];
        }
}

extern "C" void kernel_launch(void* const* d_in, const int* in_sizes, int n_in,
                              void* d_out, int out_size, void* d_ws, size_t ws_size,
                              hipStream_t stream) {
    // Inputs resolved BY ELEMENT COUNT (unique): x 4194304, W_attn 3145728,
    // b_attn 3072, W_proj 1048576, b_proj 1024. All fp32.
    const float *x = nullptr, *Wa = nullptr, *ba = nullptr, *Wp = nullptr, *bp = nullptr;
    for (int i = 0; i < n_in; ++i) {
        switch (in_sizes[i]) {
            case 4194304: x  = (const float*)d_in[i]; break;
            case 3145728: Wa = (const float*)d_in[i]; break;
            case 3072:    ba = (const float*)d_in[i]; break;
            case 1048576: Wp = (const float*)d_in[i]; break;
            case 1024:    bp = (const float*)d_in[i]; break;
            default: break;
        }
    }
    float* out = (float*)d_out;

    char* ws = (char*)d_ws;
    u16* qb     = (u16*)(ws);                    //  0.. 8 MiB  bf16 [B,H,T,D] (q*0.125*log2e)
    u16* kb     = (u16*)(ws + 8388608);          //  8..16 MiB  bf16 [B,H,T,D]
    u16* vt     = (u16*)(ws + 16777216);         // 16..24 MiB  bf16 [B,H,D,T]
    u16* yab    = (u16*)(ws + 25165824);         // 24..32 MiB  bf16 [B,T,C]
    float2* tab = (float2*)(ws + 33554432);      // 32..32.5 MiB
    u16* xb     = (u16*)(ws + 35651584);         // 34..42 MiB  bf16 [4096,1024]
    u16* Wab    = (u16*)(ws + 44040192);         // 42..48 MiB  bf16 [3072,1024]
    u16* Wpb    = (u16*)(ws + 50331648);         // 48..50 MiB  bf16 [1024,1024]

    conv_k<<<2048, 256, 0, stream>>>(x, xb, 524288);
    conv_k<<<1536, 256, 0, stream>>>(Wa, Wab, 393216);
    conv_k<<<512, 256, 0, stream>>>(Wp, Wpb, 131072);
    rope_tab_k<<<256, 256, 0, stream>>>(tab);
    qkv_rope_k<<<dim3(24, 32), 256, 0, stream>>>(xb, Wab, ba, tab, qb, kb, vt);
    flash_k<<<dim3(16, 32), 512, 0, stream>>>(qb, kb, vt, yab);
    proj_k<<<dim3(8, 32), 256, 0, stream>>>(yab, Wpb, bp, out);
}